// Round 1
// baseline (1064.806 us; speedup 1.0000x reference)
//
#include <hip/hip_runtime.h>
#include <hip/hip_bf16.h>
#include <math.h>

#define B_     16
#define L_     4096
#define H_     512
#define NH     32
#define OUT_   256
#define NPRED_ 128

typedef __attribute__((ext_vector_type(8))) short bf16x8;
typedef __attribute__((ext_vector_type(4))) float f32x4;

// ---------------- prep: select + bf16-convert weights ----------------
// Wsel[256][512]: rows 0..127 = conv_w[384+r], rows 128..255 = conv_w[896+(r-128)]
// outw[256][4096] = bf16(out_w)   (o-major, matches B-frag staging Bs[col][k])
// bsel[256] f32
__global__ void prep_kernel(const float* __restrict__ conv_w, const float* __restrict__ conv_b,
                            const float* __restrict__ out_w,
                            __hip_bfloat16* __restrict__ Wsel, float* __restrict__ bselp,
                            __hip_bfloat16* __restrict__ outw)
{
    int idx = blockIdx.x * blockDim.x + threadIdx.x;
    if (idx < 256 * 512) {
        int r = idx >> 9, hcol = idx & 511;
        int src = (r < 128) ? (384 + r) : (768 + r);   // 896 + (r-128)
        Wsel[idx] = __float2bfloat16(conv_w[src * H_ + hcol]);
    } else if (idx < 256 * 512 + 256 * 4096) {
        int i2 = idx - 256 * 512;
        outw[i2] = __float2bfloat16(out_w[i2]);
    } else if (idx < 256 * 512 + 256 * 4096 + 256) {
        int r = idx - 256 * 512 - 256 * 4096;
        int src = (r < 128) ? (384 + r) : (768 + r);
        bselp[r] = conv_b[src];
    }
}

// ---------------- scan: diagonal SSM recurrence + D*x + exact gelu ----------------
// block = 256 thr = 32 h * 8 lanes; each lane owns 4 of the 32 complex states.
// grid (B=16, H/32=16). Writes gT[b][l][h] bf16 (l-major rows => GEMM1 A-operand).
__global__ __launch_bounds__(256)
void scan_kernel(const float* __restrict__ inp, const float* __restrict__ C,
                 const float* __restrict__ log_dt, const float* __restrict__ log_A_real,
                 const float* __restrict__ A_imag, const float* __restrict__ Dv,
                 __hip_bfloat16* __restrict__ gT)
{
    const int b  = blockIdx.x;
    const int h0 = blockIdx.y * 32;
    const int tid = threadIdx.x;
    const int q  = tid & 7;    // lane within h-group
    const int hl = tid >> 3;   // 0..31
    const int h  = h0 + hl;

    __shared__ float xs[128][33];  // [l_local][h_local], +1 pad for epilogue strided read
    __shared__ float ys[32][129];  // [h_local][l_local], pad kills write conflicts
    __shared__ float Ds[32];
    if (tid < 32) Ds[tid] = Dv[h0 + tid];

    const float dt = expf(log_dt[h]);
    float wr[4], wi[4], cr[4], cni[4];
    float sr[4] = {0.f, 0.f, 0.f, 0.f}, si[4] = {0.f, 0.f, 0.f, 0.f};
#pragma unroll
    for (int j = 0; j < 4; ++j) {
        const int n = q * 4 + j;
        const float Ar = -expf(log_A_real[h * NH + n]);
        const float Ai = A_imag[h * NH + n];
        const float ar = Ar * dt, ai = Ai * dt;
        const float er = expf(ar);
        const float wrr = er * cosf(ai);
        const float wii = er * sinf(ai);
        // (w-1)/A  (complex divide)
        const float m2 = Ar * Ar + Ai * Ai;
        const float nr = wrr - 1.0f, nim = wii;
        const float qr = (nr * Ar + nim * Ai) / m2;
        const float qi = (nim * Ar - nr * Ai) / m2;
        const float Cr = C[(h * NH + n) * 2 + 0];
        const float Ci = C[(h * NH + n) * 2 + 1];
        wr[j]  = wrr;  wi[j] = wii;
        cr[j]  =  2.0f * (Cr * qr - Ci * qi);
        cni[j] = -2.0f * (Cr * qi + Ci * qr);   // y += cr*Sr + cni*Si
    }

    const size_t inp_base = (size_t)b * L_ * H_ + h0;
    for (int c = 0; c < L_ / 128; ++c) {
        const int l0 = c * 128;
        __syncthreads();   // xs/ys reuse guard (and covers Ds on first iter)
#pragma unroll
        for (int k = 0; k < 16; ++k) {
            int idx = tid + k * 256;          // 0..4095
            int ll = idx >> 5, hh = idx & 31; // coalesced: 32 consecutive h = 128B/row
            xs[ll][hh] = inp[inp_base + (size_t)(l0 + ll) * H_ + hh];
        }
        __syncthreads();
#pragma unroll 4
        for (int ll = 0; ll < 128; ++ll) {
            const float x = xs[ll][hl];       // broadcast within 8-lane group
            float y = 0.0f;
#pragma unroll
            for (int j = 0; j < 4; ++j) {
                const float nsr = fmaf(wr[j], sr[j], fmaf(-wi[j], si[j], x));
                const float nsi = fmaf(wr[j], si[j], wi[j] * sr[j]);
                sr[j] = nsr; si[j] = nsi;
                y = fmaf(cr[j], nsr, y);
                y = fmaf(cni[j], nsi, y);
            }
            y += __shfl_xor(y, 1);
            y += __shfl_xor(y, 2);
            y += __shfl_xor(y, 4);
            if (q == 0) ys[hl][ll] = y;
        }
        __syncthreads();
#pragma unroll
        for (int k = 0; k < 16; ++k) {
            int idx = tid + k * 256;
            int ll = idx >> 5, hh = idx & 31;
            float v = ys[hh][ll] + Ds[hh] * xs[ll][hh];
            float ge = 0.5f * v * (1.0f + erff(v * 0.70710678f));   // exact gelu
            gT[((size_t)b * L_ + l0 + ll) * H_ + h0 + hh] = __float2bfloat16(ge);
        }
    }
}

__device__ __forceinline__ unsigned short bf16bits(float f) {
    __hip_bfloat16 hv = __float2bfloat16(f);
    return *reinterpret_cast<unsigned short*>(&hv);
}

// ---------------- GEMM1 + gate: z^T[l][o] = gT[l][:] . Wsel[o][:] ; gated = za*sig(zb) ----------------
// per block: 128 l-rows x 256 o-cols (full M of the selected rows), K=512, BK=32.
// 8 waves; wave (wrr 0..1, wcc 0..3) covers rows wrr*64, col strips {wcc*32, 128+wcc*32}
// so the (o, o+128) gate pair is register-local per lane.
__global__ __launch_bounds__(512)
void gemm1_kernel(const __hip_bfloat16* __restrict__ gT, const __hip_bfloat16* __restrict__ Wsel,
                  const float* __restrict__ bsel, __hip_bfloat16* __restrict__ gated)
{
    const int b  = blockIdx.y;
    const int l0 = blockIdx.x * 128;
    const int tid = threadIdx.x;
    const int wid = tid >> 6, lane = tid & 63;
    const int wrr = wid >> 2;      // 0..1
    const int wcc = wid & 3;       // 0..3
    const int lr  = lane & 15;
    const int lk8 = (lane >> 4) * 8;

    __shared__ short As[128][40];  // [l][k] +8 pad: 2-way max on b128 frag reads
    __shared__ short Bs[256][40];  // [o][k]

    f32x4 acc[4][4];
#pragma unroll
    for (int i = 0; i < 4; ++i)
#pragma unroll
        for (int j = 0; j < 4; ++j) acc[i][j] = (f32x4){0.f, 0.f, 0.f, 0.f};

    const short* gsrc = (const short*)gT + ((size_t)b * L_ + l0) * H_;
    const short* wsrc = (const short*)Wsel;
    const int arow = tid >> 2, aseg = tid & 3;

    for (int ks = 0; ks < 16; ++ks) {
        const int k0 = ks * 32;
        uint4 av  = *(const uint4*)(gsrc + (size_t)arow * H_ + k0 + aseg * 8);
        uint4 bv0 = *(const uint4*)(wsrc + (size_t)arow * 512 + k0 + aseg * 8);
        uint4 bv1 = *(const uint4*)(wsrc + (size_t)(arow + 128) * 512 + k0 + aseg * 8);
        *(uint4*)&As[arow][aseg * 8]       = av;
        *(uint4*)&Bs[arow][aseg * 8]       = bv0;
        *(uint4*)&Bs[arow + 128][aseg * 8] = bv1;
        __syncthreads();

        bf16x8 af[4], bfr[4];
#pragma unroll
        for (int mi = 0; mi < 4; ++mi)
            af[mi] = *(const bf16x8*)&As[wrr * 64 + mi * 16 + lr][lk8];
#pragma unroll
        for (int ni = 0; ni < 4; ++ni) {
            int col = (ni < 2) ? (wcc * 32 + ni * 16) : (128 + wcc * 32 + (ni - 2) * 16);
            bfr[ni] = *(const bf16x8*)&Bs[col + lr][lk8];
        }
#pragma unroll
        for (int mi = 0; mi < 4; ++mi)
#pragma unroll
            for (int ni = 0; ni < 4; ++ni)
                acc[mi][ni] = __builtin_amdgcn_mfma_f32_16x16x32_bf16(af[mi], bfr[ni], acc[mi][ni], 0, 0, 0);
        __syncthreads();
    }

    // epilogue: bias + gate, write gated[b][hh][l] bf16 (hh-major rows for GEMM2 A)
    const int lj4 = (lane >> 4) * 4;
#pragma unroll
    for (int mi = 0; mi < 4; ++mi) {
#pragma unroll
        for (int ni = 0; ni < 2; ++ni) {
            const int oa = wcc * 32 + ni * 16 + lr;       // 0..127 == hh
            const float ba  = bsel[oa];
            const float bbv = bsel[oa + 128];
            ushort4 pack;
            unsigned short* pu = (unsigned short*)&pack;
#pragma unroll
            for (int j = 0; j < 4; ++j) {
                float za = acc[mi][ni][j] + ba;
                float zb = acc[mi][ni + 2][j] + bbv;
                float gv = za * (1.0f / (1.0f + expf(-zb)));
                pu[j] = bf16bits(gv);
            }
            const int lrow = l0 + wrr * 64 + mi * 16 + lj4;  // 4 consecutive l
            *(ushort4*)((unsigned short*)gated + ((size_t)b * NPRED_ + oa) * L_ + lrow) = pack;
        }
    }
}

// ---------------- GEMM2: out2[hh][o] = sum_l gated[hh][l]*outw[o][l]; write out[b][o][hh] ----------------
__global__ __launch_bounds__(256)
void gemm2_kernel(const __hip_bfloat16* __restrict__ gated, const __hip_bfloat16* __restrict__ outw,
                  const float* __restrict__ outb, float* __restrict__ outp)
{
    const int b  = blockIdx.y;
    const int o0 = blockIdx.x * 128;
    const int tid = threadIdx.x;
    const int wid = tid >> 6, lane = tid & 63;
    const int wrr = wid >> 1;      // 0..1 rows
    const int wcc = wid & 1;       // 0..1 cols
    const int lr  = lane & 15;
    const int lk8 = (lane >> 4) * 8;

    __shared__ short As[128][40];  // [hh][k]
    __shared__ short Bs[128][40];  // [o][k]

    f32x4 acc[4][4];
#pragma unroll
    for (int i = 0; i < 4; ++i)
#pragma unroll
        for (int j = 0; j < 4; ++j) acc[i][j] = (f32x4){0.f, 0.f, 0.f, 0.f};

    const short* asrc = (const short*)gated + (size_t)b * NPRED_ * L_;
    const short* bsrc = (const short*)outw + (size_t)o0 * L_;
    const int arow = tid >> 2, aseg = tid & 3;   // rows 0..63, two passes

    for (int ks = 0; ks < 128; ++ks) {
        const int k0 = ks * 32;
        uint4 a0 = *(const uint4*)(asrc + (size_t)arow * L_ + k0 + aseg * 8);
        uint4 a1 = *(const uint4*)(asrc + (size_t)(arow + 64) * L_ + k0 + aseg * 8);
        uint4 b0 = *(const uint4*)(bsrc + (size_t)arow * L_ + k0 + aseg * 8);
        uint4 b1 = *(const uint4*)(bsrc + (size_t)(arow + 64) * L_ + k0 + aseg * 8);
        *(uint4*)&As[arow][aseg * 8]      = a0;
        *(uint4*)&As[arow + 64][aseg * 8] = a1;
        *(uint4*)&Bs[arow][aseg * 8]      = b0;
        *(uint4*)&Bs[arow + 64][aseg * 8] = b1;
        __syncthreads();

        bf16x8 af[4], bfr[4];
#pragma unroll
        for (int mi = 0; mi < 4; ++mi)
            af[mi] = *(const bf16x8*)&As[wrr * 64 + mi * 16 + lr][lk8];
#pragma unroll
        for (int ni = 0; ni < 4; ++ni)
            bfr[ni] = *(const bf16x8*)&Bs[wcc * 64 + ni * 16 + lr][lk8];
#pragma unroll
        for (int mi = 0; mi < 4; ++mi)
#pragma unroll
            for (int ni = 0; ni < 4; ++ni)
                acc[mi][ni] = __builtin_amdgcn_mfma_f32_16x16x32_bf16(af[mi], bfr[ni], acc[mi][ni], 0, 0, 0);
        __syncthreads();
    }

    const int lj4 = (lane >> 4) * 4;
#pragma unroll
    for (int mi = 0; mi < 4; ++mi) {
#pragma unroll
        for (int ni = 0; ni < 4; ++ni) {
            const int og = o0 + wcc * 64 + ni * 16 + lr;
            const float bo = outb[og];
            float4 v;
            v.x = acc[mi][ni][0] + bo;
            v.y = acc[mi][ni][1] + bo;
            v.z = acc[mi][ni][2] + bo;
            v.w = acc[mi][ni][3] + bo;
            const int hh = wrr * 64 + mi * 16 + lj4;   // 4 consecutive hh
            *(float4*)(outp + ((size_t)b * OUT_ + og) * NPRED_ + hh) = v;
        }
    }
}

// ---------------- launch ----------------
extern "C" void kernel_launch(void* const* d_in, const int* in_sizes, int n_in,
                              void* d_out, int out_size, void* d_ws, size_t ws_size,
                              hipStream_t stream)
{
    const float* inp        = (const float*)d_in[0];
    // d_in[1] = spec : unused by the reference
    const float* C          = (const float*)d_in[2];
    const float* log_dt     = (const float*)d_in[3];
    const float* log_A_real = (const float*)d_in[4];
    const float* A_imag     = (const float*)d_in[5];
    const float* Dv         = (const float*)d_in[6];
    const float* conv_w     = (const float*)d_in[7];
    const float* conv_b     = (const float*)d_in[8];
    const float* out_w      = (const float*)d_in[9];
    const float* out_b      = (const float*)d_in[10];
    float* outp = (float*)d_out;

    // workspace layout (bytes)
    const size_t off_gT    = 0;                          // 16*4096*512*2  = 64 MiB
    const size_t off_gated = off_gT    + 67108864;       // 16*128*4096*2  = 16 MiB
    const size_t off_Wsel  = off_gated + 16777216;       // 256*512*2
    const size_t off_outw  = off_Wsel  + 262144;         // 256*4096*2
    const size_t off_bsel  = off_outw  + 2097152;        // 256*4
    const size_t need      = off_bsel + 1024;
    if (ws_size < need) return;   // loud failure rather than corruption

    char* ws = (char*)d_ws;
    __hip_bfloat16* gT    = (__hip_bfloat16*)(ws + off_gT);
    __hip_bfloat16* gated = (__hip_bfloat16*)(ws + off_gated);
    __hip_bfloat16* Wsel  = (__hip_bfloat16*)(ws + off_Wsel);
    __hip_bfloat16* outw  = (__hip_bfloat16*)(ws + off_outw);
    float*          bselp = (float*)(ws + off_bsel);

    const int prep_total = 256 * 512 + 256 * 4096 + 256;
    prep_kernel<<<(prep_total + 255) / 256, 256, 0, stream>>>(conv_w, conv_b, out_w, Wsel, bselp, outw);
    scan_kernel<<<dim3(16, 16), 256, 0, stream>>>(inp, C, log_dt, log_A_real, A_imag, Dv, gT);
    gemm1_kernel<<<dim3(32, 16), 512, 0, stream>>>(gT, Wsel, bselp, gated);
    gemm2_kernel<<<dim3(2, 16), 256, 0, stream>>>(gated, outw, out_b, outp);
}

// Round 3
// 612.556 us; speedup vs baseline: 1.7383x; 1.7383x over previous
//
#include <hip/hip_runtime.h>
#include <hip/hip_bf16.h>
#include <math.h>

#define B_     16
#define L_     4096
#define H_     512
#define NH     32
#define OUT_   256
#define NPRED_ 128
#define CCH    8      // chunks along L
#define LCH    512    // chunk length

typedef __attribute__((ext_vector_type(8))) short bf16x8;
typedef __attribute__((ext_vector_type(4))) float f32x4;

// ---------------- prep: select + bf16-convert weights ----------------
__global__ void prep_kernel(const float* __restrict__ conv_w, const float* __restrict__ conv_b,
                            const float* __restrict__ out_w,
                            __hip_bfloat16* __restrict__ Wsel, float* __restrict__ bselp,
                            __hip_bfloat16* __restrict__ outw)
{
    int idx = blockIdx.x * blockDim.x + threadIdx.x;
    if (idx < 256 * 512) {
        int r = idx >> 9, hcol = idx & 511;
        int src = (r < 128) ? (384 + r) : (768 + r);   // 896 + (r-128)
        Wsel[idx] = __float2bfloat16(conv_w[src * H_ + hcol]);
    } else if (idx < 256 * 512 + 256 * 4096) {
        int i2 = idx - 256 * 512;
        outw[i2] = __float2bfloat16(out_w[i2]);
    } else if (idx < 256 * 512 + 256 * 4096 + 256) {
        int r = idx - 256 * 512 - 256 * 4096;
        int src = (r < 128) ? (384 + r) : (768 + r);
        bselp[r] = conv_b[src];
    }
}

// ---------------- scan pass1: per-chunk state from zero init ----------------
// grid (16 b, 16 hgroup, 8 chunk), block 256 = 32h x 8q, 4 states/lane.
__global__ __launch_bounds__(256)
void scan_pass1(const float* __restrict__ inp, const float* __restrict__ log_dt,
                const float* __restrict__ log_A_real, const float* __restrict__ A_imag,
                float2* __restrict__ M)
{
    const int b = blockIdx.x, hg = blockIdx.y, c = blockIdx.z;
    const int h0 = hg * 32;
    const int tid = threadIdx.x;
    const int q = tid & 7, hl = tid >> 3, h = h0 + hl;

    __shared__ float xs[128][33];

    float wr[4], wi[4], sr[4] = {0,0,0,0}, si[4] = {0,0,0,0};
    const float dt = expf(log_dt[h]);
#pragma unroll
    for (int j = 0; j < 4; ++j) {
        const int n = q * 4 + j;
        const float Ar = -expf(log_A_real[h * NH + n]);
        const float Ai = A_imag[h * NH + n];
        const float er = expf(Ar * dt);
        wr[j] = er * cosf(Ai * dt);
        wi[j] = er * sinf(Ai * dt);
    }

    const size_t base = (size_t)b * L_ * H_ + (size_t)c * LCH * H_ + h0;
    for (int sub = 0; sub < 4; ++sub) {
#pragma unroll
        for (int k = 0; k < 16; ++k) {
            int idx = tid + k * 256;
            int ll = idx >> 5, hh = idx & 31;
            xs[ll][hh] = inp[base + (size_t)(sub * 128 + ll) * H_ + hh];
        }
        __syncthreads();
#pragma unroll 4
        for (int ll = 0; ll < 128; ++ll) {
            const float x = xs[ll][hl];
#pragma unroll
            for (int j = 0; j < 4; ++j) {
                const float nsr = fmaf(wr[j], sr[j], fmaf(-wi[j], si[j], x));
                const float nsi = fmaf(wr[j], si[j], wi[j] * sr[j]);
                sr[j] = nsr; si[j] = nsi;
            }
        }
        __syncthreads();
    }
#pragma unroll
    for (int j = 0; j < 4; ++j)
        M[(((size_t)b * CCH + c) * H_ + h) * NH + q * 4 + j] = make_float2(sr[j], si[j]);
}

// ---------------- scan pass2: combine chunk carries ----------------
// one thread per (b,h,n); sequential over 8 chunks. Sin[c] = state entering chunk c.
__global__ __launch_bounds__(256)
void scan_pass2(const float* __restrict__ log_dt, const float* __restrict__ log_A_real,
                const float* __restrict__ A_imag, const float2* __restrict__ M,
                float2* __restrict__ Sin)
{
    const int idx = blockIdx.x * 256 + threadIdx.x;    // 262144 total
    const int n = idx & 31, h = (idx >> 5) & 511, b = idx >> 14;
    const float dt = expf(log_dt[h]);
    const float Ar = -expf(log_A_real[h * NH + n]);
    const float Ai = A_imag[h * NH + n];
    const float er = expf(Ar * dt);
    float wr = er * cosf(Ai * dt), wi = er * sinf(Ai * dt);
    // w^512 via 9 squarings (avoids large-argument trig)
#pragma unroll
    for (int s = 0; s < 9; ++s) {
        float nr = wr * wr - wi * wi;
        float ni = 2.0f * wr * wi;
        wr = nr; wi = ni;
    }
    float sre = 0.f, sim = 0.f;
#pragma unroll
    for (int c = 0; c < CCH; ++c) {
        const size_t mi_ = (((size_t)b * CCH + c) * H_ + h) * NH + n;
        float2 m = M[mi_];
        Sin[mi_] = make_float2(sre, sim);
        float nr = fmaf(wr, sre, fmaf(-wi, sim, m.x));
        float ni = fmaf(wr, sim, fmaf(wi, sre, m.y));
        sre = nr; sim = ni;
    }
}

// ---------------- scan pass3: per-chunk scan with carry + D*x + gelu -> gT bf16 ----------------
__global__ __launch_bounds__(256)
void scan_pass3(const float* __restrict__ inp, const float* __restrict__ C,
                const float* __restrict__ log_dt, const float* __restrict__ log_A_real,
                const float* __restrict__ A_imag, const float* __restrict__ Dv,
                const float2* __restrict__ Sin, __hip_bfloat16* __restrict__ gT)
{
    const int b = blockIdx.x, hg = blockIdx.y, c = blockIdx.z;
    const int h0 = hg * 32;
    const int tid = threadIdx.x;
    const int q = tid & 7, hl = tid >> 3, h = h0 + hl;

    __shared__ float xs[128][33];
    __shared__ float ys[32][129];
    __shared__ float Ds[32];
    if (tid < 32) Ds[tid] = Dv[h0 + tid];

    const float dt = expf(log_dt[h]);
    float wr[4], wi[4], cr[4], cni[4], sr[4], si[4];
#pragma unroll
    for (int j = 0; j < 4; ++j) {
        const int n = q * 4 + j;
        const float Ar = -expf(log_A_real[h * NH + n]);
        const float Ai = A_imag[h * NH + n];
        const float er = expf(Ar * dt);
        const float wrr = er * cosf(Ai * dt);
        const float wii = er * sinf(Ai * dt);
        const float m2 = Ar * Ar + Ai * Ai;
        const float nr = wrr - 1.0f, nim = wii;
        const float qr = (nr * Ar + nim * Ai) / m2;
        const float qi = (nim * Ar - nr * Ai) / m2;
        const float Cr = C[(h * NH + n) * 2 + 0];
        const float Ci = C[(h * NH + n) * 2 + 1];
        wr[j]  = wrr;  wi[j] = wii;
        cr[j]  =  2.0f * (Cr * qr - Ci * qi);
        cni[j] = -2.0f * (Cr * qi + Ci * qr);
        float2 sv = Sin[(((size_t)b * CCH + c) * H_ + h) * NH + n];
        sr[j] = sv.x; si[j] = sv.y;
    }

    const size_t base = (size_t)b * L_ * H_ + (size_t)c * LCH * H_ + h0;
    __syncthreads();   // Ds visible
    for (int sub = 0; sub < 4; ++sub) {
        const int l0 = c * LCH + sub * 128;
#pragma unroll
        for (int k = 0; k < 16; ++k) {
            int idx = tid + k * 256;
            int ll = idx >> 5, hh = idx & 31;
            xs[ll][hh] = inp[base + (size_t)(sub * 128 + ll) * H_ + hh];
        }
        __syncthreads();
#pragma unroll 4
        for (int ll = 0; ll < 128; ++ll) {
            const float x = xs[ll][hl];
            float y = 0.0f;
#pragma unroll
            for (int j = 0; j < 4; ++j) {
                const float nsr = fmaf(wr[j], sr[j], fmaf(-wi[j], si[j], x));
                const float nsi = fmaf(wr[j], si[j], wi[j] * sr[j]);
                sr[j] = nsr; si[j] = nsi;
                y = fmaf(cr[j], nsr, y);
                y = fmaf(cni[j], nsi, y);
            }
            y += __shfl_xor(y, 1);
            y += __shfl_xor(y, 2);
            y += __shfl_xor(y, 4);
            if (q == 0) ys[hl][ll] = y;
        }
        __syncthreads();
#pragma unroll
        for (int k = 0; k < 16; ++k) {
            int idx = tid + k * 256;
            int ll = idx >> 5, hh = idx & 31;
            float v = ys[hh][ll] + Ds[hh] * xs[ll][hh];
            float ge = 0.5f * v * (1.0f + erff(v * 0.70710678f));
            gT[((size_t)b * L_ + l0 + ll) * H_ + h0 + hh] = __float2bfloat16(ge);
        }
        __syncthreads();   // before next sub overwrites xs/ys
    }
}

__device__ __forceinline__ unsigned short bf16bits(float f) {
    __hip_bfloat16 hv = __float2bfloat16(f);
    return *reinterpret_cast<unsigned short*>(&hv);
}

// ---------------- GEMM1 + gate ----------------
__global__ __launch_bounds__(512)
void gemm1_kernel(const __hip_bfloat16* __restrict__ gT, const __hip_bfloat16* __restrict__ Wsel,
                  const float* __restrict__ bsel, __hip_bfloat16* __restrict__ gated)
{
    const int b  = blockIdx.y;
    const int l0 = blockIdx.x * 128;
    const int tid = threadIdx.x;
    const int wid = tid >> 6, lane = tid & 63;
    const int wrr = wid >> 2;      // 0..1
    const int wcc = wid & 3;       // 0..3
    const int lr  = lane & 15;
    const int lk8 = (lane >> 4) * 8;

    __shared__ short As[128][40];
    __shared__ short Bs[256][40];

    f32x4 acc[4][4];
#pragma unroll
    for (int i = 0; i < 4; ++i)
#pragma unroll
        for (int j = 0; j < 4; ++j) acc[i][j] = (f32x4){0.f, 0.f, 0.f, 0.f};

    const short* gsrc = (const short*)gT + ((size_t)b * L_ + l0) * H_;
    const short* wsrc = (const short*)Wsel;
    const int arow = tid >> 2, aseg = tid & 3;

    for (int ks = 0; ks < 16; ++ks) {
        const int k0 = ks * 32;
        uint4 av  = *(const uint4*)(gsrc + (size_t)arow * H_ + k0 + aseg * 8);
        uint4 bv0 = *(const uint4*)(wsrc + (size_t)arow * 512 + k0 + aseg * 8);
        uint4 bv1 = *(const uint4*)(wsrc + (size_t)(arow + 128) * 512 + k0 + aseg * 8);
        *(uint4*)&As[arow][aseg * 8]       = av;
        *(uint4*)&Bs[arow][aseg * 8]       = bv0;
        *(uint4*)&Bs[arow + 128][aseg * 8] = bv1;
        __syncthreads();

        bf16x8 af[4], bfr[4];
#pragma unroll
        for (int mi = 0; mi < 4; ++mi)
            af[mi] = *(const bf16x8*)&As[wrr * 64 + mi * 16 + lr][lk8];
#pragma unroll
        for (int ni = 0; ni < 4; ++ni) {
            int col = (ni < 2) ? (wcc * 32 + ni * 16) : (128 + wcc * 32 + (ni - 2) * 16);
            bfr[ni] = *(const bf16x8*)&Bs[col + lr][lk8];
        }
#pragma unroll
        for (int mi = 0; mi < 4; ++mi)
#pragma unroll
            for (int ni = 0; ni < 4; ++ni)
                acc[mi][ni] = __builtin_amdgcn_mfma_f32_16x16x32_bf16(af[mi], bfr[ni], acc[mi][ni], 0, 0, 0);
        __syncthreads();
    }

    const int lj4 = (lane >> 4) * 4;
#pragma unroll
    for (int mi = 0; mi < 4; ++mi) {
#pragma unroll
        for (int ni = 0; ni < 2; ++ni) {
            const int oa = wcc * 32 + ni * 16 + lr;
            const float ba  = bsel[oa];
            const float bbv = bsel[oa + 128];
            ushort4 pack;
            unsigned short* pu = (unsigned short*)&pack;
#pragma unroll
            for (int j = 0; j < 4; ++j) {
                float za = acc[mi][ni][j] + ba;
                float zb = acc[mi][ni + 2][j] + bbv;
                float gv = za * (1.0f / (1.0f + expf(-zb)));
                pu[j] = bf16bits(gv);
            }
            const int lrow = l0 + wrr * 64 + mi * 16 + lj4;
            *(ushort4*)((unsigned short*)gated + ((size_t)b * NPRED_ + oa) * L_ + lrow) = pack;
        }
    }
}

// ---------------- GEMM2: 64x64 tiles, BK=64, grid 128 blocks ----------------
__global__ __launch_bounds__(256)
void gemm2_kernel(const __hip_bfloat16* __restrict__ gated, const __hip_bfloat16* __restrict__ outw,
                  const float* __restrict__ outb, float* __restrict__ outp)
{
    const int b  = blockIdx.y;
    const int ot = blockIdx.x & 3, ht = blockIdx.x >> 2;
    const int o0 = ot * 64, hh0 = ht * 64;
    const int tid = threadIdx.x;
    const int wid = tid >> 6, lane = tid & 63;
    const int wrr = wid >> 1;      // 0..1
    const int wcc = wid & 1;       // 0..1
    const int lr  = lane & 15;
    const int lk8 = (lane >> 4) * 8;

    __shared__ short As[64][72];   // [hh][k] BK=64, +8 pad
    __shared__ short Bs[64][72];   // [o][k]

    f32x4 acc[2][2];
#pragma unroll
    for (int i = 0; i < 2; ++i)
#pragma unroll
        for (int j = 0; j < 2; ++j) acc[i][j] = (f32x4){0.f, 0.f, 0.f, 0.f};

    const short* asrc = (const short*)gated + ((size_t)b * NPRED_ + hh0) * L_;
    const short* bsrc = (const short*)outw + (size_t)o0 * L_;
    const int row = tid >> 2, seg = tid & 3;

    for (int ks = 0; ks < 64; ++ks) {
        const int k0 = ks * 64;
        uint4 a0 = *(const uint4*)(asrc + (size_t)row * L_ + k0 + seg * 8);
        uint4 a1 = *(const uint4*)(asrc + (size_t)row * L_ + k0 + 32 + seg * 8);
        uint4 b0 = *(const uint4*)(bsrc + (size_t)row * L_ + k0 + seg * 8);
        uint4 b1 = *(const uint4*)(bsrc + (size_t)row * L_ + k0 + 32 + seg * 8);
        __syncthreads();
        *(uint4*)&As[row][seg * 8]      = a0;
        *(uint4*)&As[row][32 + seg * 8] = a1;
        *(uint4*)&Bs[row][seg * 8]      = b0;
        *(uint4*)&Bs[row][32 + seg * 8] = b1;
        __syncthreads();

#pragma unroll
        for (int kk = 0; kk < 2; ++kk) {
            bf16x8 af[2], bfv[2];
#pragma unroll
            for (int mi = 0; mi < 2; ++mi)
                af[mi] = *(const bf16x8*)&As[wrr * 32 + mi * 16 + lr][kk * 32 + lk8];
#pragma unroll
            for (int ni = 0; ni < 2; ++ni)
                bfv[ni] = *(const bf16x8*)&Bs[wcc * 32 + ni * 16 + lr][kk * 32 + lk8];
#pragma unroll
            for (int mi = 0; mi < 2; ++mi)
#pragma unroll
                for (int ni = 0; ni < 2; ++ni)
                    acc[mi][ni] = __builtin_amdgcn_mfma_f32_16x16x32_bf16(af[mi], bfv[ni], acc[mi][ni], 0, 0, 0);
        }
    }

    const int lj4 = (lane >> 4) * 4;
#pragma unroll
    for (int mi = 0; mi < 2; ++mi) {
#pragma unroll
        for (int ni = 0; ni < 2; ++ni) {
            const int og = o0 + wcc * 32 + ni * 16 + lr;
            const float bo = outb[og];
            float4 v;
            v.x = acc[mi][ni][0] + bo;
            v.y = acc[mi][ni][1] + bo;
            v.z = acc[mi][ni][2] + bo;
            v.w = acc[mi][ni][3] + bo;
            const int hh = hh0 + wrr * 32 + mi * 16 + lj4;
            *(float4*)(outp + ((size_t)b * OUT_ + og) * NPRED_ + hh) = v;
        }
    }
}

// ---------------- launch ----------------
extern "C" void kernel_launch(void* const* d_in, const int* in_sizes, int n_in,
                              void* d_out, int out_size, void* d_ws, size_t ws_size,
                              hipStream_t stream)
{
    const float* inp        = (const float*)d_in[0];
    const float* C          = (const float*)d_in[2];
    const float* log_dt     = (const float*)d_in[3];
    const float* log_A_real = (const float*)d_in[4];
    const float* A_imag     = (const float*)d_in[5];
    const float* Dv         = (const float*)d_in[6];
    const float* conv_w     = (const float*)d_in[7];
    const float* conv_b     = (const float*)d_in[8];
    const float* out_w      = (const float*)d_in[9];
    const float* out_b      = (const float*)d_in[10];
    float* outp = (float*)d_out;

    // workspace layout (bytes); M aliases gT (dead before gT written),
    // Sin aliases gated (dead before gated written) -> need == 86246400 (proven available)
    const size_t off_Wsel  = 0;                         // 262144
    const size_t off_outw  = 262144;                    // 2097152
    const size_t off_bsel  = 2359296;                   // 1024
    const size_t off_gT    = 2360320;                   // 67108864
    const size_t off_gated = 69469184;                  // 16777216
    const size_t off_M     = off_gT;                    // 16*8*512*32*8 = 16777216
    const size_t off_Sin   = off_gated;                 // 16777216
    const size_t need      = 86246400;
    if (ws_size < need) return;

    char* ws = (char*)d_ws;
    __hip_bfloat16* Wsel  = (__hip_bfloat16*)(ws + off_Wsel);
    __hip_bfloat16* outw  = (__hip_bfloat16*)(ws + off_outw);
    float*          bselp = (float*)(ws + off_bsel);
    __hip_bfloat16* gT    = (__hip_bfloat16*)(ws + off_gT);
    __hip_bfloat16* gated = (__hip_bfloat16*)(ws + off_gated);
    float2*         M     = (float2*)(ws + off_M);
    float2*         Sin   = (float2*)(ws + off_Sin);

    const int prep_total = 256 * 512 + 256 * 4096 + 256;
    prep_kernel<<<(prep_total + 255) / 256, 256, 0, stream>>>(conv_w, conv_b, out_w, Wsel, bselp, outw);
    scan_pass1<<<dim3(16, 16, CCH), 256, 0, stream>>>(inp, log_dt, log_A_real, A_imag, M);
    scan_pass2<<<1024, 256, 0, stream>>>(log_dt, log_A_real, A_imag, M, Sin);
    scan_pass3<<<dim3(16, 16, CCH), 256, 0, stream>>>(inp, C, log_dt, log_A_real, A_imag, Dv, Sin, gT);
    gemm1_kernel<<<dim3(32, 16), 512, 0, stream>>>(gT, Wsel, bselp, gated);
    gemm2_kernel<<<dim3(8, 16), 256, 0, stream>>>(gated, outw, out_b, outp);
}